// Round 2
// baseline (777.526 us; speedup 1.0000x reference)
//
#include <hip/hip_runtime.h>
#include <math.h>

// B=16, T=8192, C=64, K=2 taps, 13 layers, dilation 2^l
#define CCH 64
#define TSEQ 8192
#define BATCH 16
#define NLAYERS 13
#define BT (BATCH * TSEQ)                  // 131072 positions
#define PLANE ((size_t)BT * CCH)           // 8388608 elems per bf16 plane

typedef unsigned short u16;
typedef __attribute__((ext_vector_type(8))) short bf16x8;   // 4 VGPR MFMA operand
typedef __attribute__((ext_vector_type(4))) short s16x4;
typedef __attribute__((ext_vector_type(4))) float f32x4;

__device__ __forceinline__ u16 f2bf(float f) {              // RNE fp32->bf16
    unsigned u = __float_as_uint(f);
    u += 0x7fffu + ((u >> 16) & 1u);
    return (u16)(u >> 16);
}
__device__ __forceinline__ float bf2f(u16 h) {
    return __uint_as_float(((unsigned)h) << 16);
}

// ---- pre-pass 1: x fp32 -> (hi, lo) bf16 planes (shared by both stacks at layer 0)
__global__ __launch_bounds__(256)
void convert_x(const float* __restrict__ x, u16* __restrict__ xh, u16* __restrict__ xl)
{
    const size_t i4 = (size_t)blockIdx.x * 256 + threadIdx.x;   // float4 index
    float4 v = ((const float4*)x)[i4];
    u16 h0 = f2bf(v.x), h1 = f2bf(v.y), h2 = f2bf(v.z), h3 = f2bf(v.w);
    s16x4 hv = {(short)h0, (short)h1, (short)h2, (short)h3};
    s16x4 lv = {(short)f2bf(v.x - bf2f(h0)), (short)f2bf(v.y - bf2f(h1)),
                (short)f2bf(v.z - bf2f(h2)), (short)f2bf(v.w - bf2f(h3))};
    *(s16x4*)(xh + i4 * 4) = hv;
    *(s16x4*)(xl + i4 * 4) = lv;
}

// ---- pre-pass 2: W (13,2,C,C) fp32 -> W^T[co][ci] (hi,lo) bf16, both stacks
// WT layout: [stack][layer][tap][plane][co*64+ci], plane stride 4096
__global__ __launch_bounds__(256)
void prep_w(const float* __restrict__ Wf, const float* __restrict__ Wg, u16* __restrict__ WT)
{
    const int idx = blockIdx.x * 256 + threadIdx.x;   // 0..212991
    const int s   = idx / 106496;                     // 13*2*4096
    const int r   = idx % 106496;
    const int l   = r / 8192;
    const int r2  = r % 8192;
    const int tap = r2 >> 12;
    const int ci  = (r2 >> 6) & 63;
    const int co  = r2 & 63;
    const float* W = s ? Wg : Wf;
    const float w = W[((l * 2 + tap) * 64 + ci) * 64 + co];
    const u16 hb = f2bf(w);
    const u16 lb = f2bf(w - bf2f(hb));
    const size_t base = ((((size_t)s * NLAYERS + l) * 2 + tap) * 2) * 4096 + (size_t)co * 64 + ci;
    WT[base] = hb;          // hi plane
    WT[base + 4096] = lb;   // lo plane
}

// ---- layer kernel: y[p] = x[p]*W[1] + x[p-d]*W[0], split-bf16 MFMA (3 products)
// Block: 256 thr = 4 waves; block tile 256 pos x 64 co; wave tile 128 pos x 32 co.
// A-frags: contiguous bf16x8 from [pos][ch] planes (no LDS, no transpose).
// B-frags: contiguous bf16x8 from W^T, register-resident (16 frags = 64 VGPR).
__global__ __launch_bounds__(256)
void dconv_mfma(const u16* __restrict__ xfh, const u16* __restrict__ xfl,
                const u16* __restrict__ xgh, const u16* __restrict__ xgl,
                u16* __restrict__ yfh, u16* __restrict__ yfl,
                u16* __restrict__ ygh, u16* __restrict__ ygl,
                const u16* __restrict__ WT, int layer, int d)
{
    const int stack = blockIdx.y;
    const u16* __restrict__ xh = stack ? xgh : xfh;
    const u16* __restrict__ xl = stack ? xgl : xfl;
    u16* __restrict__ yh = stack ? ygh : yfh;
    u16* __restrict__ yl = stack ? ygl : yfl;
    const u16* __restrict__ wt = WT + (size_t)(stack * NLAYERS + layer) * 16384;

    const int tid  = threadIdx.x;
    const int lane = tid & 63;
    const int wv   = tid >> 6;
    const int lm   = lane & 15;            // m (or n / co) within tile
    const int lg   = lane >> 4;            // k-chunk group 0..3
    const int p0   = blockIdx.x * 256;
    const int wpos = (wv >> 1) * 128;
    const int cw   = (wv & 1) * 32;
    const int t0   = p0 & (TSEQ - 1);

    // B[tap][kstep][plane][nt]: B[k][n] = W[ci=k][co=n]; lane holds W^T[n][k0+lg*8 .. +7]
    bf16x8 B[2][2][2][2];
#pragma unroll
    for (int tap = 0; tap < 2; ++tap)
#pragma unroll
        for (int ks = 0; ks < 2; ++ks)
#pragma unroll
            for (int pl = 0; pl < 2; ++pl)
#pragma unroll
                for (int nt = 0; nt < 2; ++nt)
                    B[tap][ks][pl][nt] = *(const bf16x8*)(wt + (tap * 2 + pl) * 4096
                                          + (cw + nt * 16 + lm) * 64 + ks * 32 + lg * 8);

    f32x4 acc[8][2];
#pragma unroll
    for (int mt = 0; mt < 8; ++mt) {
        acc[mt][0] = (f32x4){0.f, 0.f, 0.f, 0.f};
        acc[mt][1] = (f32x4){0.f, 0.f, 0.f, 0.f};
    }

    const bf16x8 zfrag = {};
#pragma unroll
    for (int tp = 0; tp < 2; ++tp) {           // tp=0: cur tap (W[1]); tp=1: prev (W[0])
        const int wtap = tp ? 0 : 1;
        const int doff = tp ? d : 0;
#pragma unroll
        for (int ks = 0; ks < 2; ++ks) {
            const int col = ks * 32 + lg * 8;  // ci base for this lane
#pragma unroll
            for (int half = 0; half < 2; ++half) {
                bf16x8 Ah[4], Al[4];
#pragma unroll
                for (int i = 0; i < 4; ++i) {
                    const int mt   = half * 4 + i;
                    const int lrow = wpos + mt * 16 + lm;
                    const bool ok  = (t0 + lrow) >= doff;          // folds away for tp=0
                    const size_t src = (size_t)(p0 + lrow - (ok ? doff : 0));
                    Ah[i] = *(const bf16x8*)(xh + src * CCH + col);
                    Al[i] = *(const bf16x8*)(xl + src * CCH + col);
                    if (!ok) { Ah[i] = zfrag; Al[i] = zfrag; }
                }
#pragma unroll
                for (int i = 0; i < 4; ++i) {
                    const int mt = half * 4 + i;
#pragma unroll
                    for (int nt = 0; nt < 2; ++nt) {
                        acc[mt][nt] = __builtin_amdgcn_mfma_f32_16x16x32_bf16(
                            Ah[i], B[wtap][ks][0][nt], acc[mt][nt], 0, 0, 0);
                        acc[mt][nt] = __builtin_amdgcn_mfma_f32_16x16x32_bf16(
                            Ah[i], B[wtap][ks][1][nt], acc[mt][nt], 0, 0, 0);
                        acc[mt][nt] = __builtin_amdgcn_mfma_f32_16x16x32_bf16(
                            Al[i], B[wtap][ks][0][nt], acc[mt][nt], 0, 0, 0);
                    }
                }
            }
        }
    }

    // D layout: col = lane&15, row = (lane>>4)*4 + r  [m89-verified]
#pragma unroll
    for (int mt = 0; mt < 8; ++mt)
#pragma unroll
        for (int nt = 0; nt < 2; ++nt)
#pragma unroll
            for (int r = 0; r < 4; ++r) {
                const size_t row = (size_t)p0 + wpos + mt * 16 + lg * 4 + r;
                const int co = cw + nt * 16 + lm;
                const float v = acc[mt][nt][r];
                const u16 hb = f2bf(v);
                yh[row * CCH + co] = hb;
                yl[row * CCH + co] = f2bf(v - bf2f(hb));
            }
}

// ---- epilogue: out = tanh(F + h@Vf) * sigmoid(G + h@Vg), F/G = hi+lo
__global__ __launch_bounds__(256)
void epilogue(const u16* __restrict__ Fh, const u16* __restrict__ Fl,
              const u16* __restrict__ Gh, const u16* __restrict__ Gl,
              const float* __restrict__ h, const float* __restrict__ Vf,
              const float* __restrict__ Vg, float* __restrict__ out)
{
    __shared__ float hvf[CCH], hvg[CCH];
    const int tid = threadIdx.x;
    const size_t p0 = (size_t)blockIdx.x * 128;
    const int b = (int)(p0 >> 13);
    if (tid < CCH) {
        float sf = 0.f, sg = 0.f;
#pragma unroll
        for (int ci = 0; ci < CCH; ++ci) {
            const float hb = h[b * CCH + ci];
            sf = fmaf(hb, Vf[ci * CCH + tid], sf);
            sg = fmaf(hb, Vg[ci * CCH + tid], sg);
        }
        hvf[tid] = sf; hvg[tid] = sg;
    }
    __syncthreads();

    const size_t base = p0 * CCH;
#pragma unroll
    for (int it = 0; it < 8; ++it) {
        const int idx = tid + it * 256;          // group of 4 elems
        const size_t e = base + (size_t)idx * 4;
        const int c0 = (idx * 4) & 63;
        const s16x4 fh = *(const s16x4*)(Fh + e);
        const s16x4 fl = *(const s16x4*)(Fl + e);
        const s16x4 gh = *(const s16x4*)(Gh + e);
        const s16x4 gl = *(const s16x4*)(Gl + e);
        float o[4];
#pragma unroll
        for (int j = 0; j < 4; ++j) {
            const float fv = bf2f((u16)fh[j]) + bf2f((u16)fl[j]) + hvf[c0 + j];
            const float gv = bf2f((u16)gh[j]) + bf2f((u16)gl[j]) + hvg[c0 + j];
            o[j] = tanhf(fv) * (1.f / (1.f + __expf(-gv)));
        }
        float4 ov = make_float4(o[0], o[1], o[2], o[3]);
        ((float4*)out)[base / 4 + idx] = ov;
    }
}

extern "C" void kernel_launch(void* const* d_in, const int* in_sizes, int n_in,
                              void* d_out, int out_size, void* d_ws, size_t ws_size,
                              hipStream_t stream)
{
    const float* x  = (const float*)d_in[0];
    const float* h  = (const float*)d_in[1];
    const float* Wf = (const float*)d_in[2];
    const float* Wg = (const float*)d_in[3];
    const float* Vf = (const float*)d_in[4];
    const float* Vg = (const float*)d_in[5];
    float* out = (float*)d_out;

    // ws layout: [WT: 1 MB pad][xh][xl][fA_h][fA_l][gA_h][gA_l]  (6 planes = 100.7 MB)
    // fB aliases the x planes (dead after layer 0); gB aliases d_out (2 planes exactly).
    u16* WT  = (u16*)d_ws;
    u16* xh  = WT + (1u << 19);
    u16* xl  = xh + PLANE;
    u16* fAh = xl + PLANE;  u16* fAl = fAh + PLANE;
    u16* gAh = fAl + PLANE; u16* gAl = gAh + PLANE;
    u16* fBh = xh;          u16* fBl = xl;
    u16* gBh = (u16*)d_out; u16* gBl = gBh + PLANE;

    convert_x<<<dim3(PLANE / 4 / 256), 256, 0, stream>>>(x, xh, xl);
    prep_w<<<dim3(832), 256, 0, stream>>>(Wf, Wg, WT);

    const u16 *cfh = xh, *cfl = xl, *cgh = xh, *cgl = xl;
    for (int l = 0; l < NLAYERS; ++l) {
        const bool even = !(l & 1);
        u16* ofh = even ? fAh : fBh;  u16* ofl = even ? fAl : fBl;
        u16* ogh = even ? gAh : gBh;  u16* ogl = even ? gAl : gBl;
        dconv_mfma<<<dim3(BT / 256, 2), 256, 0, stream>>>(cfh, cfl, cgh, cgl,
                                                          ofh, ofl, ogh, ogl,
                                                          WT, l, 1 << l);
        cfh = ofh; cfl = ofl; cgh = ogh; cgl = ogl;
    }
    // 13 layers end even -> final activations in the A buffers (ws), clear of d_out
    epilogue<<<dim3(BT / 128), 256, 0, stream>>>(cfh, cfl, cgh, cgl, h, Vf, Vg, out);
}

// Round 5
// 613.402 us; speedup vs baseline: 1.2676x; 1.2676x over previous
//
#include <hip/hip_runtime.h>
#include <math.h>

// B=16, T=8192, C=64, K=2 taps, 13 layers, dilation 2^l
#define CCH 64
#define TSEQ 8192
#define BATCH 16
#define NLAYERS 13
#define BT (BATCH * TSEQ)                  // 131072 positions
#define PLANE ((size_t)BT * CCH)           // 8388608 elems per bf16 plane

typedef unsigned short u16;
typedef unsigned int u32;
typedef __attribute__((ext_vector_type(8))) short bf16x8;   // 4 VGPR MFMA operand
typedef __attribute__((ext_vector_type(4))) short s16x4;
typedef __attribute__((ext_vector_type(4))) float f32x4;

__device__ __forceinline__ u16 f2bf(float f) {              // RNE fp32->bf16
    unsigned u = __float_as_uint(f);
    u += 0x7fffu + ((u >> 16) & 1u);
    return (u16)(u >> 16);
}
__device__ __forceinline__ float bf2f(u16 h) {
    return __uint_as_float(((unsigned)h) << 16);
}

// ---- pre-pass 1: x fp32 -> (hi, lo) bf16 planes
__global__ __launch_bounds__(256)
void convert_x(const float* __restrict__ x, u16* __restrict__ xh, u16* __restrict__ xl)
{
    const size_t i4 = (size_t)blockIdx.x * 256 + threadIdx.x;   // float4 index
    float4 v = ((const float4*)x)[i4];
    u16 h0 = f2bf(v.x), h1 = f2bf(v.y), h2 = f2bf(v.z), h3 = f2bf(v.w);
    s16x4 hv = {(short)h0, (short)h1, (short)h2, (short)h3};
    s16x4 lv = {(short)f2bf(v.x - bf2f(h0)), (short)f2bf(v.y - bf2f(h1)),
                (short)f2bf(v.z - bf2f(h2)), (short)f2bf(v.w - bf2f(h3))};
    *(s16x4*)(xh + i4 * 4) = hv;
    *(s16x4*)(xl + i4 * 4) = lv;
}

// ---- pre-pass 2: W (13,2,C,C) fp32 -> W^T[co][ci] (hi,lo) bf16, both stacks
// WT layout: [stack][layer][tap][plane][co*64+ci], plane stride 4096
__global__ __launch_bounds__(256)
void prep_w(const float* __restrict__ Wf, const float* __restrict__ Wg, u16* __restrict__ WT)
{
    const int idx = blockIdx.x * 256 + threadIdx.x;   // 0..212991
    const int s   = idx / 106496;                     // 13*2*4096
    const int r   = idx % 106496;
    const int l   = r / 8192;
    const int r2  = r % 8192;
    const int tap = r2 >> 12;
    const int ci  = (r2 >> 6) & 63;
    const int co  = r2 & 63;
    const float* W = s ? Wg : Wf;
    const float w = W[((l * 2 + tap) * 64 + ci) * 64 + co];
    const u16 hb = f2bf(w);
    const u16 lb = f2bf(w - bf2f(hb));
    const size_t base = ((((size_t)s * NLAYERS + l) * 2 + tap) * 2) * 4096 + (size_t)co * 64 + ci;
    WT[base] = hb;          // hi plane
    WT[base + 4096] = lb;   // lo plane
}

// ---- pre-pass 3: hv[s][b][co] = h[b] @ V_s  (2 x 16 x 64 fp32)
__global__ __launch_bounds__(256)
void prep_hv(const float* __restrict__ h, const float* __restrict__ Vf,
             const float* __restrict__ Vg, float* __restrict__ hv)
{
    const int idx = blockIdx.x * 256 + threadIdx.x;   // 0..2047
    const int s  = idx >> 10;
    const int b  = (idx >> 6) & 15;
    const int co = idx & 63;
    const float* V = s ? Vg : Vf;
    float acc = 0.f;
#pragma unroll
    for (int ci = 0; ci < CCH; ++ci)
        acc = fmaf(h[b * CCH + ci], V[ci * CCH + co], acc);
    hv[idx] = acc;
}

// ---- layer kernel (layers 0..6): y[p] = x[p]*W[1] + x[p-d]*W[0], split-bf16 MFMA.
// Operand-swapped: D = W^T (A) * x^T (B)  ->  D[m=co][n=pos], 8B packed stores.
// grid.x = 2048 (1024 tiles x 2 stacks) with XCD-chunked bijective swizzle.
__global__ __launch_bounds__(256, 4)
void dconv_mfma(const u16* __restrict__ xfh, const u16* __restrict__ xfl,
                const u16* __restrict__ xgh, const u16* __restrict__ xgl,
                u16* __restrict__ yfh, u16* __restrict__ yfl,
                u16* __restrict__ ygh, u16* __restrict__ ygl,
                const u16* __restrict__ WT, int layer, int d)
{
    const int bx = blockIdx.x;                       // 0..2047
    const int v  = (bx & 7) * 256 + (bx >> 3);       // XCD k owns v in [k*256,(k+1)*256)
    const int stack = v >> 10;
    const int tile  = v & 1023;

    const u16* __restrict__ xh = stack ? xgh : xfh;
    const u16* __restrict__ xl = stack ? xgl : xfl;
    u16* __restrict__ yh = stack ? ygh : yfh;
    u16* __restrict__ yl = stack ? ygl : yfl;
    const u16* __restrict__ wt = WT + (size_t)(stack * NLAYERS + layer) * 16384;

    const int tid  = threadIdx.x;
    const int lane = tid & 63;
    const int wv   = tid >> 6;
    const int lm   = lane & 15;            // n = pos offset (B/D col), m = co offset (A row)
    const int lg   = lane >> 4;            // k-chunk 0..3 (A/B), co-quad (D)
    const int p0   = tile * 128 + (wv >> 1) * 64;    // wave pos base
    const int cw   = (wv & 1) * 32;                  // wave co base
    const int t0   = p0 & (TSEQ - 1);

    // W-hi A-frags register-resident: A[m=co][k=ci]; lane holds 8 consecutive ci.
    bf16x8 Wh[2][2][2];   // [mt][tap][ks]
#pragma unroll
    for (int mt = 0; mt < 2; ++mt)
#pragma unroll
        for (int tap = 0; tap < 2; ++tap)
#pragma unroll
            for (int ks = 0; ks < 2; ++ks)
                Wh[mt][tap][ks] = *(const bf16x8*)(wt + (tap * 2 + 0) * 4096
                                    + (cw + mt * 16 + lm) * 64 + ks * 32 + lg * 8);

    f32x4 acc[2][4];
#pragma unroll
    for (int mt = 0; mt < 2; ++mt)
#pragma unroll
        for (int nt = 0; nt < 4; ++nt) acc[mt][nt] = (f32x4){0.f, 0.f, 0.f, 0.f};

    const bf16x8 zfrag = {};
#pragma unroll
    for (int tp = 0; tp < 2; ++tp) {           // tp=0: cur tap (W idx 1); tp=1: prev (W idx 0)
        const int wtap = tp ? 0 : 1;
        const int doff = tp ? d : 0;
#pragma unroll
        for (int ks = 0; ks < 2; ++ks) {
            const int col = ks * 32 + lg * 8;
            bf16x8 Xh[4], Xl[4];
#pragma unroll
            for (int nt = 0; nt < 4; ++nt) {
                const int prow = nt * 16 + lm;
                const bool ok  = (t0 + prow) >= doff;            // folds for tp=0
                const size_t src = (size_t)(p0 + prow) - (ok ? doff : 0);
                Xh[nt] = *(const bf16x8*)(xh + src * CCH + col);
                Xl[nt] = *(const bf16x8*)(xl + src * CCH + col);
                if (!ok) { Xh[nt] = zfrag; Xl[nt] = zfrag; }
            }
            bf16x8 Wl_[2];
#pragma unroll
            for (int mt = 0; mt < 2; ++mt)
                Wl_[mt] = *(const bf16x8*)(wt + (wtap * 2 + 1) * 4096
                            + (cw + mt * 16 + lm) * 64 + ks * 32 + lg * 8);
#pragma unroll
            for (int mt = 0; mt < 2; ++mt)
#pragma unroll
                for (int nt = 0; nt < 4; ++nt) {
                    acc[mt][nt] = __builtin_amdgcn_mfma_f32_16x16x32_bf16(
                        Wh[mt][wtap][ks], Xh[nt], acc[mt][nt], 0, 0, 0);
                    acc[mt][nt] = __builtin_amdgcn_mfma_f32_16x16x32_bf16(
                        Wh[mt][wtap][ks], Xl[nt], acc[mt][nt], 0, 0, 0);
                    acc[mt][nt] = __builtin_amdgcn_mfma_f32_16x16x32_bf16(
                        Wl_[mt], Xh[nt], acc[mt][nt], 0, 0, 0);
                }
        }
    }

    // D: n=pos=lm, m=co=lg*4+r (4 consecutive co)  -> packed 8B stores (hi & lo planes)
#pragma unroll
    for (int mt = 0; mt < 2; ++mt)
#pragma unroll
        for (int nt = 0; nt < 4; ++nt) {
            const f32x4 a = acc[mt][nt];
            const size_t row = (size_t)p0 + nt * 16 + lm;
            const int co = cw + mt * 16 + lg * 4;
            const u32 u0 = __float_as_uint(a[0]), u1 = __float_as_uint(a[1]);
            const u32 u2 = __float_as_uint(a[2]), u3 = __float_as_uint(a[3]);
            const u32 h01 = (u0 >> 16) | (u1 & 0xffff0000u);
            const u32 h23 = (u2 >> 16) | (u3 & 0xffff0000u);
            const float r0 = a[0] - __uint_as_float(u0 & 0xffff0000u);
            const float r1 = a[1] - __uint_as_float(u1 & 0xffff0000u);
            const float r2 = a[2] - __uint_as_float(u2 & 0xffff0000u);
            const float r3 = a[3] - __uint_as_float(u3 & 0xffff0000u);
            const u32 l01 = (u32)f2bf(r0) | ((u32)f2bf(r1) << 16);
            const u32 l23 = (u32)f2bf(r2) | ((u32)f2bf(r3) << 16);
            uint2 hvv; hvv.x = h01; hvv.y = h23;
            uint2 lvv; lvv.x = l01; lvv.y = l23;
            *(uint2*)(yh + row * CCH + co) = hvv;
            *(uint2*)(yl + row * CCH + co) = lvv;
        }
}

// ---- fused tail: layers 7..12 (d=128..4096) + gating epilogue, via mod-128 rows.
// Row (b, r=t%128) is an independent length-64 sequence with strided dilations 1..32.
// Block = 2 rows (128 pos x 64 ch) LDS-resident hi/lo, double-buffered (64 KB).
__global__ __launch_bounds__(256, 2)
void fused_tail(const u16* __restrict__ fh, const u16* __restrict__ fl,
                const u16* __restrict__ gh, const u16* __restrict__ gl,
                const u16* __restrict__ WT, const float* __restrict__ hv,
                float* __restrict__ out)
{
    __shared__ u16 S[2][2][128 * 64];   // [buf][hi/lo][(pos*64+ch) ^ ((pos&7)<<3)]

    const int tid  = threadIdx.x;
    const int lane = tid & 63;
    const int wv   = tid >> 6;
    const int lm   = lane & 15;
    const int lg   = lane >> 4;
    const int row0 = blockIdx.x * 2;            // rows row0, row0+1
    const int myrow = row0 + (wv >> 1);         // wave's row
    const int b    = myrow >> 7;
    const size_t gbase = (size_t)b * TSEQ + (myrow & 127);   // flat pos at q=0
    const int cw   = (wv & 1) * 32;

    float tf[2][4][4];                  // tanh(f + hVf), staged across stack passes
    const bf16x8 zfrag = {};

    for (int s = 0; s < 2; ++s) {
        const u16* __restrict__ inh = s ? gh : fh;
        const u16* __restrict__ inl = s ? gl : fl;

        __syncthreads();                // prior-stack readers done before restage
        // stage 128 pos x 64 ch (hi+lo) into S[0], swizzled
#pragma unroll
        for (int pl = 0; pl < 2; ++pl) {
            const u16* __restrict__ src = pl ? inl : inh;
#pragma unroll
            for (int it = 0; it < 4; ++it) {
                const int idx = tid + it * 256;     // 16B chunk id, 0..1023
                const int pos = idx >> 3;
                const int c8  = (idx & 7) * 8;
                const int rr  = row0 + (pos >> 6);
                const int q   = pos & 63;
                const size_t gp = ((size_t)(rr >> 7) * TSEQ + (rr & 127)) + (size_t)q * 128;
                const bf16x8 val = *(const bf16x8*)(src + gp * CCH + c8);
                const int sidx = (pos * 64 + c8) ^ ((pos & 7) << 3);
                *(bf16x8*)&S[0][pl][sidx] = val;
            }
        }
        __syncthreads();

        int buf = 0;
        f32x4 acc[2][4];
        for (int l = 7; l <= 12; ++l) {
            const u16* __restrict__ wt = WT + (size_t)(s * NLAYERS + l) * 16384;
            const int delta = 1 << (l - 7);         // strided dilation
#pragma unroll
            for (int mt = 0; mt < 2; ++mt)
#pragma unroll
                for (int nt = 0; nt < 4; ++nt) acc[mt][nt] = (f32x4){0.f, 0.f, 0.f, 0.f};

#pragma unroll
            for (int tp = 0; tp < 2; ++tp) {
                const int wtap = tp ? 0 : 1;
                const int dq   = tp ? delta : 0;
#pragma unroll
                for (int ks = 0; ks < 2; ++ks) {
                    const int col = ks * 32 + lg * 8;
                    bf16x8 Xh[4], Xl[4];
#pragma unroll
                    for (int nt = 0; nt < 4; ++nt) {
                        const int q  = nt * 16 + lm;
                        const bool ok = q >= dq;
                        const int qq = ok ? (q - dq) : q;      // clamp in-range, zero below
                        const int pos = (wv >> 1) * 64 + qq;
                        const int sidx = (pos * 64 + col) ^ ((pos & 7) << 3);
                        Xh[nt] = *(const bf16x8*)&S[buf][0][sidx];
                        Xl[nt] = *(const bf16x8*)&S[buf][1][sidx];
                        if (!ok) { Xh[nt] = zfrag; Xl[nt] = zfrag; }
                    }
                    bf16x8 Wh_[2], Wl_[2];
#pragma unroll
                    for (int mt = 0; mt < 2; ++mt) {
                        Wh_[mt] = *(const bf16x8*)(wt + (wtap * 2 + 0) * 4096
                                    + (cw + mt * 16 + lm) * 64 + ks * 32 + lg * 8);
                        Wl_[mt] = *(const bf16x8*)(wt + (wtap * 2 + 1) * 4096
                                    + (cw + mt * 16 + lm) * 64 + ks * 32 + lg * 8);
                    }
#pragma unroll
                    for (int mt = 0; mt < 2; ++mt)
#pragma unroll
                        for (int nt = 0; nt < 4; ++nt) {
                            acc[mt][nt] = __builtin_amdgcn_mfma_f32_16x16x32_bf16(
                                Wh_[mt], Xh[nt], acc[mt][nt], 0, 0, 0);
                            acc[mt][nt] = __builtin_amdgcn_mfma_f32_16x16x32_bf16(
                                Wh_[mt], Xl[nt], acc[mt][nt], 0, 0, 0);
                            acc[mt][nt] = __builtin_amdgcn_mfma_f32_16x16x32_bf16(
                                Wl_[mt], Xh[nt], acc[mt][nt], 0, 0, 0);
                        }
                }
            }

            if (l < 12) {               // pack hi/lo and store to the other buffer
#pragma unroll
                for (int mt = 0; mt < 2; ++mt)
#pragma unroll
                    for (int nt = 0; nt < 4; ++nt) {
                        const f32x4 a = acc[mt][nt];
                        const int pos = (wv >> 1) * 64 + nt * 16 + lm;
                        const int co  = cw + mt * 16 + lg * 4;
                        const u32 u0 = __float_as_uint(a[0]), u1 = __float_as_uint(a[1]);
                        const u32 u2 = __float_as_uint(a[2]), u3 = __float_as_uint(a[3]);
                        const u32 h01 = (u0 >> 16) | (u1 & 0xffff0000u);
                        const u32 h23 = (u2 >> 16) | (u3 & 0xffff0000u);
                        const float r0 = a[0] - __uint_as_float(u0 & 0xffff0000u);
                        const float r1 = a[1] - __uint_as_float(u1 & 0xffff0000u);
                        const float r2 = a[2] - __uint_as_float(u2 & 0xffff0000u);
                        const float r3 = a[3] - __uint_as_float(u3 & 0xffff0000u);
                        const u32 l01 = (u32)f2bf(r0) | ((u32)f2bf(r1) << 16);
                        const u32 l23 = (u32)f2bf(r2) | ((u32)f2bf(r3) << 16);
                        const int sidx = (pos * 64 + co) ^ ((pos & 7) << 3);
                        uint2 hvv; hvv.x = h01; hvv.y = h23;
                        uint2 lvv; lvv.x = l01; lvv.y = l23;
                        *(uint2*)&S[buf ^ 1][0][sidx] = hvv;
                        *(uint2*)&S[buf ^ 1][1][sidx] = lvv;
                    }
                __syncthreads();
                buf ^= 1;
            }
        }

        // epilogue: s=0 stages tanh(f+hVf); s=1 combines with sigmoid(g+hVg), stores fp32
#pragma unroll
        for (int mt = 0; mt < 2; ++mt) {
            const int co = cw + mt * 16 + lg * 4;
            const float4 bias = *(const float4*)(hv + (s * 16 + b) * CCH + co);
            const float bb[4] = {bias.x, bias.y, bias.z, bias.w};
#pragma unroll
            for (int nt = 0; nt < 4; ++nt) {
                if (s == 0) {
#pragma unroll
                    for (int rg = 0; rg < 4; ++rg)
                        tf[mt][nt][rg] = tanhf(acc[mt][nt][rg] + bb[rg]);
                } else {
                    const int q = nt * 16 + lm;
                    const size_t gp = gbase + (size_t)q * 128;
                    float o[4];
#pragma unroll
                    for (int rg = 0; rg < 4; ++rg) {
                        const float gv = acc[mt][nt][rg] + bb[rg];
                        o[rg] = tf[mt][nt][rg] * (1.f / (1.f + __expf(-gv)));
                    }
                    float4 ov = make_float4(o[0], o[1], o[2], o[3]);
                    *(float4*)(out + gp * CCH + co) = ov;
                }
            }
        }
    }
}

extern "C" void kernel_launch(void* const* d_in, const int* in_sizes, int n_in,
                              void* d_out, int out_size, void* d_ws, size_t ws_size,
                              hipStream_t stream)
{
    const float* x  = (const float*)d_in[0];
    const float* h  = (const float*)d_in[1];
    const float* Wf = (const float*)d_in[2];
    const float* Wg = (const float*)d_in[3];
    const float* Vf = (const float*)d_in[4];
    const float* Vg = (const float*)d_in[5];
    float* out = (float*)d_out;

    // ws: [WT 0.83MB | hv 8KB | pad to 1MB][xh][xl][fA_h][fA_l][gA_h][gA_l]
    // f: even layer -> fA (ws), odd -> fB (x planes, dead after l=0).
    // g: even layer -> gA (ws), odd -> gB (d_out alias).
    // Layers 0..6 end even -> f in fA, g in gA; tail reads fA,gA and writes d_out.
    u16* WT  = (u16*)d_ws;
    float* hvp = (float*)(WT + 458752);
    u16* xh  = WT + (1u << 19);
    u16* xl  = xh + PLANE;
    u16* fAh = xl + PLANE;  u16* fAl = fAh + PLANE;
    u16* gAh = fAl + PLANE; u16* gAl = gAh + PLANE;
    u16* fBh = xh;          u16* fBl = xl;
    u16* gBh = (u16*)d_out; u16* gBl = gBh + PLANE;

    convert_x<<<dim3(PLANE / 4 / 256), 256, 0, stream>>>(x, xh, xl);
    prep_w<<<dim3(832), 256, 0, stream>>>(Wf, Wg, WT);
    prep_hv<<<dim3(8), 256, 0, stream>>>(h, Vf, Vg, hvp);

    const u16 *cfh = xh, *cfl = xl, *cgh = xh, *cgl = xl;
    for (int l = 0; l < 7; ++l) {
        const bool even = !(l & 1);
        u16* ofh = even ? fAh : fBh;  u16* ofl = even ? fAl : fBl;
        u16* ogh = even ? gAh : gBh;  u16* ogl = even ? gAl : gBl;
        dconv_mfma<<<dim3(2048), 256, 0, stream>>>(cfh, cfl, cgh, cgl,
                                                   ofh, ofl, ogh, ogl,
                                                   WT, l, 1 << l);
        cfh = ofh; cfl = ofl; cgh = ogh; cgl = ogl;
    }
    // layers 7..12 + epilogue, fused over mod-128 rows (2048 rows / 2 per block)
    fused_tail<<<dim3(1024), 256, 0, stream>>>(cfh, cfl, cgh, cgl, WT, hvp, out);
}

// Round 8
// 470.063 us; speedup vs baseline: 1.6541x; 1.3049x over previous
//
#include <hip/hip_runtime.h>
#include <math.h>

// B=16, T=8192, C=64, K=2 taps, 13 layers, dilation 2^l
#define CCH 64
#define TSEQ 8192
#define BATCH 16
#define NLAYERS 13
#define BT (BATCH * TSEQ)                  // 131072 positions
#define PLANE ((size_t)BT * CCH)           // 8388608 elems per bf16 plane

typedef unsigned short u16;
typedef unsigned int u32;
typedef __attribute__((ext_vector_type(8))) short bf16x8;   // 4 VGPR MFMA operand
typedef __attribute__((ext_vector_type(4))) short s16x4;
typedef __attribute__((ext_vector_type(4))) float f32x4;

__device__ __forceinline__ u16 f2bf(float f) {              // RNE fp32->bf16
    unsigned u = __float_as_uint(f);
    u += 0x7fffu + ((u >> 16) & 1u);
    return (u16)(u >> 16);
}
__device__ __forceinline__ float bf2f(u16 h) {
    return __uint_as_float(((unsigned)h) << 16);
}

// ---- pre-pass: W (13,2,C,C) fp32 -> W^T[co][ci] (hi,lo) bf16, both stacks
// WT layout: [stack][layer][tap][plane][co*64+ci], plane stride 4096
__global__ __launch_bounds__(256)
void prep_w(const float* __restrict__ Wf, const float* __restrict__ Wg, u16* __restrict__ WT)
{
    const int idx = blockIdx.x * 256 + threadIdx.x;   // 0..212991
    const int s   = idx / 106496;                     // 13*2*4096
    const int r   = idx % 106496;
    const int l   = r / 8192;
    const int r2  = r % 8192;
    const int tap = r2 >> 12;
    const int ci  = (r2 >> 6) & 63;
    const int co  = r2 & 63;
    const float* W = s ? Wg : Wf;
    const float w = W[((l * 2 + tap) * 64 + ci) * 64 + co];
    const u16 hb = f2bf(w);
    const u16 lb = f2bf(w - bf2f(hb));
    const size_t base = ((((size_t)s * NLAYERS + l) * 2 + tap) * 2) * 4096 + (size_t)co * 64 + ci;
    WT[base] = hb;          // hi plane
    WT[base + 4096] = lb;   // lo plane
}

// ---- pre-pass: hv[s][b][co] = h[b] @ V_s  (2 x 16 x 64 fp32)
__global__ __launch_bounds__(256)
void prep_hv(const float* __restrict__ h, const float* __restrict__ Vf,
             const float* __restrict__ Vg, float* __restrict__ hv)
{
    const int idx = blockIdx.x * 256 + threadIdx.x;   // 0..2047
    const int s  = idx >> 10;
    const int b  = (idx >> 6) & 15;
    const int co = idx & 63;
    const float* V = s ? Vg : Vf;
    float acc = 0.f;
#pragma unroll
    for (int ci = 0; ci < CCH; ++ci)
        acc = fmaf(h[b * CCH + ci], V[ci * CCH + co], acc);
    hv[idx] = acc;
}

// ---- fused head: layers 0..6 (d=1..64) LDS-resident, in-place trapezoid.
// Block: 256 pos (128 halo + 128 out) x 64 ch, hi/lo split = 64 KB LDS.
// grid = (1024 tiles, 2 stacks). Stages fp32 x directly (absorbs convert_x).
// Per layer: read own+lookback frags -> barrier -> MFMA -> write own 64 pos -> barrier.
__global__ __launch_bounds__(256, 2)
void head_fused(const float* __restrict__ x,
                u16* __restrict__ yfh, u16* __restrict__ yfl,
                u16* __restrict__ ygh, u16* __restrict__ ygl,
                const u16* __restrict__ WT)
{
    __shared__ u16 S[2][256 * 64];   // [hi/lo][(pos*64+ch) ^ ((pos&7)<<3)]

    const int tid   = threadIdx.x;
    const int lane  = tid & 63;
    const int wv    = tid >> 6;
    const int lm    = lane & 15;
    const int lg    = lane >> 4;
    const int w0    = wv * 64;                 // wave's LDS pos base
    const int tile  = blockIdx.x;
    const int stack = blockIdx.y;
    const int b     = tile >> 6;
    const int t0loc = (tile & 63) << 7;        // output window start within batch
    const size_t bbase = (size_t)b * TSEQ;
    u16* __restrict__ yh = stack ? ygh : yfh;
    u16* __restrict__ yl = stack ? ygl : yfl;
    const u16* __restrict__ wbase = WT + (size_t)(stack * NLAYERS) * 16384;

    // ---- stage fp32 x -> hi/lo bf16 in LDS (halo before batch start = zeros)
#pragma unroll
    for (int it = 0; it < 16; ++it) {
        const int idx = tid + it * 256;        // 0..4095 float4 slots (256 pos x 16)
        const int pos = idx >> 4;
        const int c4  = (idx & 15) << 2;
        const int tl  = t0loc - 128 + pos;
        float4 v = make_float4(0.f, 0.f, 0.f, 0.f);
        if (tl >= 0) v = *(const float4*)(x + (bbase + tl) * CCH + c4);
        const u32 u0 = __float_as_uint(v.x), u1 = __float_as_uint(v.y);
        const u32 u2 = __float_as_uint(v.z), u3 = __float_as_uint(v.w);
        const u32 h01 = (u0 >> 16) | (u1 & 0xffff0000u);
        const u32 h23 = (u2 >> 16) | (u3 & 0xffff0000u);
        const float r0 = v.x - __uint_as_float(u0 & 0xffff0000u);
        const float r1 = v.y - __uint_as_float(u1 & 0xffff0000u);
        const float r2 = v.z - __uint_as_float(u2 & 0xffff0000u);
        const float r3 = v.w - __uint_as_float(u3 & 0xffff0000u);
        const u32 l01 = (u32)f2bf(r0) | ((u32)f2bf(r1) << 16);
        const u32 l23 = (u32)f2bf(r2) | ((u32)f2bf(r3) << 16);
        const int sidx = (pos * 64 + c4) ^ ((pos & 7) << 3);
        uint2 hv_; hv_.x = h01; hv_.y = h23;
        uint2 lv_; lv_.x = l01; lv_.y = l23;
        *(uint2*)&S[0][sidx] = hv_;
        *(uint2*)&S[1][sidx] = lv_;
    }
    __syncthreads();

    const bf16x8 zfrag = {};
#pragma unroll
    for (int l = 0; l < 7; ++l) {
        const int d = 1 << l;
        const u16* __restrict__ wt = wbase + (size_t)l * 16384;

        // ---- read phase: all X frags (both taps, both k-halves) into registers
        bf16x8 Xh[2][2][4], Xl[2][2][4];   // [tap][ks][nt]
#pragma unroll
        for (int tp = 0; tp < 2; ++tp) {
            const int dd = tp ? d : 0;
#pragma unroll
            for (int ks = 0; ks < 2; ++ks) {
                const int col = ks * 32 + lg * 8;
#pragma unroll
                for (int nt = 0; nt < 4; ++nt) {
                    const int p  = w0 + nt * 16 + lm;
                    const bool ok = p >= dd;               // invalid-trapezoid / causal mask
                    const int pp = ok ? (p - dd) : p;
                    const int sidx = (pp * 64 + col) ^ ((pp & 7) << 3);
                    const bf16x8 vh = *(const bf16x8*)&S[0][sidx];
                    const bf16x8 vl = *(const bf16x8*)&S[1][sidx];
                    Xh[tp][ks][nt] = ok ? vh : zfrag;
                    Xl[tp][ks][nt] = ok ? vl : zfrag;
                }
            }
        }
        __syncthreads();   // all reads complete block-wide before any write

        // ---- MFMA phase (registers + global W only)
        f32x4 acc[4][4];
#pragma unroll
        for (int mt = 0; mt < 4; ++mt)
#pragma unroll
            for (int nt = 0; nt < 4; ++nt) acc[mt][nt] = (f32x4){0.f, 0.f, 0.f, 0.f};

#pragma unroll
        for (int mt = 0; mt < 4; ++mt) {
#pragma unroll
            for (int tp = 0; tp < 2; ++tp) {
                const int wtap = tp ? 0 : 1;
#pragma unroll
                for (int ks = 0; ks < 2; ++ks) {
                    const bf16x8 Ah = *(const bf16x8*)(wt + (wtap * 2 + 0) * 4096
                                        + (mt * 16 + lm) * 64 + ks * 32 + lg * 8);
                    const bf16x8 Al = *(const bf16x8*)(wt + (wtap * 2 + 1) * 4096
                                        + (mt * 16 + lm) * 64 + ks * 32 + lg * 8);
#pragma unroll
                    for (int nt = 0; nt < 4; ++nt) {
                        acc[mt][nt] = __builtin_amdgcn_mfma_f32_16x16x32_bf16(
                            Ah, Xh[tp][ks][nt], acc[mt][nt], 0, 0, 0);
                        acc[mt][nt] = __builtin_amdgcn_mfma_f32_16x16x32_bf16(
                            Ah, Xl[tp][ks][nt], acc[mt][nt], 0, 0, 0);
                        acc[mt][nt] = __builtin_amdgcn_mfma_f32_16x16x32_bf16(
                            Al, Xh[tp][ks][nt], acc[mt][nt], 0, 0, 0);
                    }
                }
            }
        }

        // ---- write phase
        if (l < 6) {
            // pack hi/lo, write own 64 positions back in place
#pragma unroll
            for (int mt = 0; mt < 4; ++mt)
#pragma unroll
                for (int nt = 0; nt < 4; ++nt) {
                    const f32x4 a = acc[mt][nt];
                    const int pos = w0 + nt * 16 + lm;
                    const int co  = mt * 16 + lg * 4;
                    const u32 u0 = __float_as_uint(a[0]), u1 = __float_as_uint(a[1]);
                    const u32 u2 = __float_as_uint(a[2]), u3 = __float_as_uint(a[3]);
                    const u32 h01 = (u0 >> 16) | (u1 & 0xffff0000u);
                    const u32 h23 = (u2 >> 16) | (u3 & 0xffff0000u);
                    const float r0 = a[0] - __uint_as_float(u0 & 0xffff0000u);
                    const float r1 = a[1] - __uint_as_float(u1 & 0xffff0000u);
                    const float r2 = a[2] - __uint_as_float(u2 & 0xffff0000u);
                    const float r3 = a[3] - __uint_as_float(u3 & 0xffff0000u);
                    const u32 l01 = (u32)f2bf(r0) | ((u32)f2bf(r1) << 16);
                    const u32 l23 = (u32)f2bf(r2) | ((u32)f2bf(r3) << 16);
                    const int sidx = (pos * 64 + co) ^ ((pos & 7) << 3);
                    uint2 hv_; hv_.x = h01; hv_.y = h23;
                    uint2 lv_; lv_.x = l01; lv_.y = l23;
                    *(uint2*)&S[0][sidx] = hv_;
                    *(uint2*)&S[1][sidx] = lv_;
                }
            __syncthreads();
        } else if (w0 >= 128) {
            // final layer: waves 2,3 hold the valid 128 output positions -> global
#pragma unroll
            for (int mt = 0; mt < 4; ++mt)
#pragma unroll
                for (int nt = 0; nt < 4; ++nt) {
                    const f32x4 a = acc[mt][nt];
                    const size_t row = bbase + t0loc + (w0 - 128) + nt * 16 + lm;
                    const int co = mt * 16 + lg * 4;
                    const u32 u0 = __float_as_uint(a[0]), u1 = __float_as_uint(a[1]);
                    const u32 u2 = __float_as_uint(a[2]), u3 = __float_as_uint(a[3]);
                    const u32 h01 = (u0 >> 16) | (u1 & 0xffff0000u);
                    const u32 h23 = (u2 >> 16) | (u3 & 0xffff0000u);
                    const float r0 = a[0] - __uint_as_float(u0 & 0xffff0000u);
                    const float r1 = a[1] - __uint_as_float(u1 & 0xffff0000u);
                    const float r2 = a[2] - __uint_as_float(u2 & 0xffff0000u);
                    const float r3 = a[3] - __uint_as_float(u3 & 0xffff0000u);
                    const u32 l01 = (u32)f2bf(r0) | ((u32)f2bf(r1) << 16);
                    const u32 l23 = (u32)f2bf(r2) | ((u32)f2bf(r3) << 16);
                    uint2 hv_; hv_.x = h01; hv_.y = h23;
                    uint2 lv_; lv_.x = l01; lv_.y = l23;
                    *(uint2*)(yh + row * CCH + co) = hv_;
                    *(uint2*)(yl + row * CCH + co) = lv_;
                }
        }
    }
}

// ---- fused tail: layers 7..12 (d=128..4096) + gating epilogue, via mod-128 rows.
// (unchanged from measured r4 kernel — 133.7 us control)
__global__ __launch_bounds__(256, 2)
void fused_tail(const u16* __restrict__ fh, const u16* __restrict__ fl,
                const u16* __restrict__ gh, const u16* __restrict__ gl,
                const u16* __restrict__ WT, const float* __restrict__ hv,
                float* __restrict__ out)
{
    __shared__ u16 S[2][2][128 * 64];   // [buf][hi/lo][(pos*64+ch) ^ ((pos&7)<<3)]

    const int tid  = threadIdx.x;
    const int lane = tid & 63;
    const int wv   = tid >> 6;
    const int lm   = lane & 15;
    const int lg   = lane >> 4;
    const int row0 = blockIdx.x * 2;            // rows row0, row0+1
    const int myrow = row0 + (wv >> 1);         // wave's row
    const int b    = myrow >> 7;
    const size_t gbase = (size_t)b * TSEQ + (myrow & 127);   // flat pos at q=0
    const int cw   = (wv & 1) * 32;

    float tf[2][4][4];                  // tanh(f + hVf), staged across stack passes
    const bf16x8 zfrag = {};

    for (int s = 0; s < 2; ++s) {
        const u16* __restrict__ inh = s ? gh : fh;
        const u16* __restrict__ inl = s ? gl : fl;

        __syncthreads();                // prior-stack readers done before restage
#pragma unroll
        for (int pl = 0; pl < 2; ++pl) {
            const u16* __restrict__ src = pl ? inl : inh;
#pragma unroll
            for (int it = 0; it < 4; ++it) {
                const int idx = tid + it * 256;     // 16B chunk id, 0..1023
                const int pos = idx >> 3;
                const int c8  = (idx & 7) * 8;
                const int rr  = row0 + (pos >> 6);
                const int q   = pos & 63;
                const size_t gp = ((size_t)(rr >> 7) * TSEQ + (rr & 127)) + (size_t)q * 128;
                const bf16x8 val = *(const bf16x8*)(src + gp * CCH + c8);
                const int sidx = (pos * 64 + c8) ^ ((pos & 7) << 3);
                *(bf16x8*)&S[0][pl][sidx] = val;
            }
        }
        __syncthreads();

        int buf = 0;
        f32x4 acc[2][4];
        for (int l = 7; l <= 12; ++l) {
            const u16* __restrict__ wt = WT + (size_t)(s * NLAYERS + l) * 16384;
            const int delta = 1 << (l - 7);         // strided dilation
#pragma unroll
            for (int mt = 0; mt < 2; ++mt)
#pragma unroll
                for (int nt = 0; nt < 4; ++nt) acc[mt][nt] = (f32x4){0.f, 0.f, 0.f, 0.f};

#pragma unroll
            for (int tp = 0; tp < 2; ++tp) {
                const int wtap = tp ? 0 : 1;
                const int dq   = tp ? delta : 0;
#pragma unroll
                for (int ks = 0; ks < 2; ++ks) {
                    const int col = ks * 32 + lg * 8;
                    bf16x8 Xh[4], Xl[4];
#pragma unroll
                    for (int nt = 0; nt < 4; ++nt) {
                        const int q  = nt * 16 + lm;
                        const bool ok = q >= dq;
                        const int qq = ok ? (q - dq) : q;      // clamp in-range, zero below
                        const int pos = (wv >> 1) * 64 + qq;
                        const int sidx = (pos * 64 + col) ^ ((pos & 7) << 3);
                        Xh[nt] = *(const bf16x8*)&S[buf][0][sidx];
                        Xl[nt] = *(const bf16x8*)&S[buf][1][sidx];
                        if (!ok) { Xh[nt] = zfrag; Xl[nt] = zfrag; }
                    }
                    bf16x8 Wh_[2], Wl_[2];
#pragma unroll
                    for (int mt = 0; mt < 2; ++mt) {
                        Wh_[mt] = *(const bf16x8*)(wt + (wtap * 2 + 0) * 4096
                                    + (cw + mt * 16 + lm) * 64 + ks * 32 + lg * 8);
                        Wl_[mt] = *(const bf16x8*)(wt + (wtap * 2 + 1) * 4096
                                    + (cw + mt * 16 + lm) * 64 + ks * 32 + lg * 8);
                    }
#pragma unroll
                    for (int mt = 0; mt < 2; ++mt)
#pragma unroll
                        for (int nt = 0; nt < 4; ++nt) {
                            acc[mt][nt] = __builtin_amdgcn_mfma_f32_16x16x32_bf16(
                                Wh_[mt], Xh[nt], acc[mt][nt], 0, 0, 0);
                            acc[mt][nt] = __builtin_amdgcn_mfma_f32_16x16x32_bf16(
                                Wh_[mt], Xl[nt], acc[mt][nt], 0, 0, 0);
                            acc[mt][nt] = __builtin_amdgcn_mfma_f32_16x16x32_bf16(
                                Wl_[mt], Xh[nt], acc[mt][nt], 0, 0, 0);
                        }
                }
            }

            if (l < 12) {               // pack hi/lo and store to the other buffer
#pragma unroll
                for (int mt = 0; mt < 2; ++mt)
#pragma unroll
                    for (int nt = 0; nt < 4; ++nt) {
                        const f32x4 a = acc[mt][nt];
                        const int pos = (wv >> 1) * 64 + nt * 16 + lm;
                        const int co  = cw + mt * 16 + lg * 4;
                        const u32 u0 = __float_as_uint(a[0]), u1 = __float_as_uint(a[1]);
                        const u32 u2 = __float_as_uint(a[2]), u3 = __float_as_uint(a[3]);
                        const u32 h01 = (u0 >> 16) | (u1 & 0xffff0000u);
                        const u32 h23 = (u2 >> 16) | (u3 & 0xffff0000u);
                        const float r0 = a[0] - __uint_as_float(u0 & 0xffff0000u);
                        const float r1 = a[1] - __uint_as_float(u1 & 0xffff0000u);
                        const float r2 = a[2] - __uint_as_float(u2 & 0xffff0000u);
                        const float r3 = a[3] - __uint_as_float(u3 & 0xffff0000u);
                        const u32 l01 = (u32)f2bf(r0) | ((u32)f2bf(r1) << 16);
                        const u32 l23 = (u32)f2bf(r2) | ((u32)f2bf(r3) << 16);
                        const int sidx = (pos * 64 + co) ^ ((pos & 7) << 3);
                        uint2 hvv; hvv.x = h01; hvv.y = h23;
                        uint2 lvv; lvv.x = l01; lvv.y = l23;
                        *(uint2*)&S[buf ^ 1][0][sidx] = hvv;
                        *(uint2*)&S[buf ^ 1][1][sidx] = lvv;
                    }
                __syncthreads();
                buf ^= 1;
            }
        }

        // epilogue: s=0 stages tanh(f+hVf); s=1 combines with sigmoid(g+hVg), stores fp32
#pragma unroll
        for (int mt = 0; mt < 2; ++mt) {
            const int co = cw + mt * 16 + lg * 4;
            const float4 bias = *(const float4*)(hv + (s * 16 + b) * CCH + co);
            const float bb[4] = {bias.x, bias.y, bias.z, bias.w};
#pragma unroll
            for (int nt = 0; nt < 4; ++nt) {
                if (s == 0) {
#pragma unroll
                    for (int rg = 0; rg < 4; ++rg)
                        tf[mt][nt][rg] = tanhf(acc[mt][nt][rg] + bb[rg]);
                } else {
                    const int q = nt * 16 + lm;
                    const size_t gp = gbase + (size_t)q * 128;
                    float o[4];
#pragma unroll
                    for (int rg = 0; rg < 4; ++rg) {
                        const float gv = acc[mt][nt][rg] + bb[rg];
                        o[rg] = tf[mt][nt][rg] * (1.f / (1.f + __expf(-gv)));
                    }
                    float4 ov = make_float4(o[0], o[1], o[2], o[3]);
                    *(float4*)(out + gp * CCH + co) = ov;
                }
            }
        }
    }
}

extern "C" void kernel_launch(void* const* d_in, const int* in_sizes, int n_in,
                              void* d_out, int out_size, void* d_ws, size_t ws_size,
                              hipStream_t stream)
{
    const float* x  = (const float*)d_in[0];
    const float* h  = (const float*)d_in[1];
    const float* Wf = (const float*)d_in[2];
    const float* Wg = (const float*)d_in[3];
    const float* Vf = (const float*)d_in[4];
    const float* Vg = (const float*)d_in[5];
    float* out = (float*)d_out;

    // ws: [WT 0.83MB | hv 8KB | pad to 1MB][fA_h][fA_l][gA_h][gA_l]  (~68 MB)
    u16* WT   = (u16*)d_ws;
    float* hvp = (float*)(WT + 458752);
    u16* fAh = WT + (1u << 19);
    u16* fAl = fAh + PLANE;
    u16* gAh = fAl + PLANE;
    u16* gAl = gAh + PLANE;

    prep_w<<<dim3(832), 256, 0, stream>>>(Wf, Wg, WT);
    prep_hv<<<dim3(8), 256, 0, stream>>>(h, Vf, Vg, hvp);

    // layers 0..6 fused, LDS-resident (1024 tiles x 2 stacks); absorbs convert_x
    head_fused<<<dim3(BT / 128, 2), 256, 0, stream>>>(x, fAh, fAl, gAh, gAl, WT);

    // layers 7..12 + epilogue, fused over mod-128 rows (2048 rows / 2 per block)
    fused_tail<<<dim3(1024), 256, 0, stream>>>(fAh, fAl, gAh, gAl, WT, hvp, out);
}